// Round 18
// baseline (169.923 us; speedup 1.0000x reference)
//
#include <hip/hip_runtime.h>
#include <hip/hip_bf16.h>

// B=4, N0=2048 (N=1024 diff + 1024 cond), C=768, H=12, hd=64. All fp32 I/O.
// SINGLE f16 everywhere (R13-R15); fixed-max softmax (R16).
// R18: GEMM loop = R16's proven 2-phase 32KB dbuf (R17's 3-buf pipeline cut
// occupancy 25->15% and regressed). C^T epilogue for q/k kept, but via a
// SEPARATE template instantiation (single MFMA path -> no VGPR bloat):
//   EPI 0: qkv q/k tiles (bx<12), swapped MFMA -> C^T -> ushort4 stores
//   EPI 3: qkv v tiles, normal orientation -> vt f16 T
//   EPI 1: proj -> fp32 d_out[:, N:]. EPI 2: proj -> vt2 f16 T.
// Lessons held: MFMA operands from LDS (R9); many small attn blocks (R10);
// no setprio/defer-max in lockstep attn (R11); occupancy > pipeline depth
// at 128^2 tile (R6, R17).

#define C_DIM 768
#define HEADS 12
#define HD 64
#define NSEQ 1024
#define BATCH 4
#define SZC 3145728  // BATCH*HEADS*NSEQ*HD

typedef short bf16x8 __attribute__((ext_vector_type(8)));       // raw 16-bit x8
typedef _Float16 f16x8 __attribute__((ext_vector_type(8)));
typedef float f32x4 __attribute__((ext_vector_type(4)));
typedef unsigned int u32x4v __attribute__((ext_vector_type(4)));

typedef __attribute__((address_space(3))) unsigned int lds_u32_t;
typedef __attribute__((address_space(1))) const unsigned int glb_u32_t;

__device__ __forceinline__ void gl16(const void* g, void* l) {
  __builtin_amdgcn_global_load_lds((glb_u32_t*)g, (lds_u32_t*)l, 16, 0, 0);
}

__device__ __forceinline__ unsigned short f2h(float x) {
  _Float16 h = (_Float16)x;
  return *reinterpret_cast<unsigned short*>(&h);
}

// ---------------------------------------------------------------------------
// Merged weight prep: 4 weights -> wT f16 single, z selects.
// ---------------------------------------------------------------------------
__global__ __launch_bounds__(256) void split_wT4_k(
    const float* __restrict__ w0, const float* __restrict__ w1,
    const float* __restrict__ w2, const float* __restrict__ w3,
    unsigned short* __restrict__ t0, unsigned short* __restrict__ t1,
    unsigned short* __restrict__ t2, unsigned short* __restrict__ t3)
{
  const int z = blockIdx.z;
  const int N = (z < 2) ? 2304 : 768;
  if (blockIdx.x * 32 >= N) return;
  const float* w = (z == 0) ? w0 : (z == 1) ? w1 : (z == 2) ? w2 : w3;
  unsigned short* th = (z == 0) ? t0 : (z == 1) ? t1 : (z == 2) ? t2 : t3;

  __shared__ float T[32][33];
  const int n0 = blockIdx.x * 32, k0 = blockIdx.y * 32;
  const int tx = threadIdx.x, ty = threadIdx.y;
#pragma unroll
  for (int i = 0; i < 4; ++i) {
    int k = ty + i * 8;
    T[k][tx] = w[(size_t)(k0 + k) * N + n0 + tx];
  }
  __syncthreads();
#pragma unroll
  for (int i = 0; i < 4; ++i) {
    int n = ty + i * 8;
    th[(size_t)(n0 + n) * 768 + k0 + tx] = f2h(T[tx][n]);
  }
}

// ---------------------------------------------------------------------------
// x prep: elementwise f16 convert of x -> xs.
// ---------------------------------------------------------------------------
__global__ __launch_bounds__(256) void split_x_k(
    const float* __restrict__ x, unsigned short* __restrict__ xs)
{
  const size_t i = ((size_t)blockIdx.x * 256 + threadIdx.x) * 8;
  float4 f0 = *(const float4*)(x + i);
  float4 f1 = *(const float4*)(x + i + 4);
  float fa[8] = {f0.x, f0.y, f0.z, f0.w, f1.x, f1.y, f1.z, f1.w};
  unsigned short hv[8];
#pragma unroll
  for (int j = 0; j < 8; ++j) hv[j] = f2h(fa[j]);
  *(bf16x8*)(xs + i) = *(bf16x8*)hv;
}

// ---------------------------------------------------------------------------
// Unified single-f16 GEMM, 2-phase dbuf (R16 structure), all-gl16
// (pre-swizzled sources, chunk^((row>>1)&3)). 128x128 tile, BK=32, 4 waves,
// LDS 32 KB (16 KB/buffer).
// EPI 0: qkv q/k (bx<12 range, grid.x=12): SWAPPED MFMA -> C^T, ushort4.
// EPI 3: qkv v (grid.x=6, c0=(12+bx)*128): normal -> vt f16 T.
// EPI 1: proj -> fp32 d_out[:, N:]. EPI 2: proj -> vt2 f16 T.
// ---------------------------------------------------------------------------
template <int EPI>
__global__ __launch_bounds__(256) void gemm2_k(
    const unsigned short* __restrict__ A,
    const unsigned short* __restrict__ B0, const unsigned short* __restrict__ B1,
    const float* __restrict__ bias,
    unsigned short* __restrict__ ws_split,
    float* __restrict__ outf,
    unsigned short* __restrict__ vt_out)
{
  __shared__ __attribute__((aligned(16))) unsigned short lds[16384];  // 32 KB

  const int tid = threadIdx.x;
  const int lane = tid & 63;
  const int wave = tid >> 6;
  const int wr = wave >> 1, wc = wave & 1;
  const int arow = lane & 15, agrp = lane >> 4;

  int bx, by, half;
  if constexpr (EPI == 0) {
    int flat = blockIdx.x + 12 * blockIdx.y + 384 * blockIdx.z;  // nwg=768
    flat = (flat & 7) * 96 + (flat >> 3);
    bx = flat % 12;
    int rest = flat / 12;
    by = rest & 31;
    half = rest >> 5;
  } else if constexpr (EPI == 3) {
    int flat = blockIdx.x + 6 * blockIdx.y + 192 * blockIdx.z;   // nwg=384
    flat = (flat & 7) * 48 + (flat >> 3);
    bx = flat % 6;
    int rest = flat / 6;
    by = rest & 31;
    half = rest >> 5;
  } else {
    int flat = blockIdx.x + 6 * blockIdx.y;  // nwg = 192
    flat = (flat & 7) * 24 + (flat >> 3);
    bx = flat % 6;
    by = flat / 6;
    half = 0;
  }

  const int m0 = by * 128;
  const int b = m0 >> 10, nloc = m0 & 1023;
  const int c0 = (EPI == 3) ? (12 + bx) * 128 : bx * 128;
  const bool qkv_mode = (EPI == 0 || EPI == 3);
  const unsigned short* __restrict__ Bp = (qkv_mode && half) ? B1 : B0;
  const size_t Arow = qkv_mode ? (size_t)(b * 2048 + half * 1024 + nloc)
                               : (size_t)m0;

  const int gr = tid >> 2, gc = (tid & 3) ^ ((tid >> 3) & 3);
  const unsigned short* gA = A + (Arow + gr) * 768 + gc * 8;
  const unsigned short* gB = Bp + (size_t)(c0 + gr) * 768 + gc * 8;
  const int wo = wave * 512;

  f32x4 acc[4][4];
#pragma unroll
  for (int i = 0; i < 4; ++i)
#pragma unroll
    for (int j = 0; j < 4; ++j) acc[i][j] = f32x4{0.f, 0.f, 0.f, 0.f};

  auto stage4 = [&](int k0, int bo) {
    gl16(gA + k0, lds + bo + wo);
    gl16(gA + k0 + 64 * 768, lds + bo + wo + 2048);
    gl16(gB + k0, lds + bo + 4096 + wo);
    gl16(gB + k0 + 64 * 768, lds + bo + 4096 + wo + 2048);
  };

  stage4(0, 0);
  asm volatile("s_waitcnt vmcnt(0)" ::: "memory");
  __builtin_amdgcn_s_barrier();

  int cur = 0;
  for (int t = 0; t < 24; ++t) {
    const int bo = cur * 8192;
    if (t < 23) stage4((t + 1) * 32, bo ^ 8192);

    f16x8 af[4], bf[4];
#pragma unroll
    for (int mf = 0; mf < 4; ++mf) {
      const int row = wr * 64 + mf * 16 + arow;
      const int off = bo + row * 32 + ((agrp ^ ((row >> 1) & 3)) << 3);
      af[mf] = *(const f16x8*)(lds + off);
    }
#pragma unroll
    for (int nf = 0; nf < 4; ++nf) {
      const int row = wc * 64 + nf * 16 + arow;
      const int off = bo + row * 32 + ((agrp ^ ((row >> 1) & 3)) << 3);
      bf[nf] = *(const f16x8*)(lds + 4096 + off);
    }
    if constexpr (EPI == 0) {
      // swapped operands: acc = B^T A = C^T fragmentwise
#pragma unroll
      for (int mf = 0; mf < 4; ++mf)
#pragma unroll
        for (int nf = 0; nf < 4; ++nf)
          acc[mf][nf] = __builtin_amdgcn_mfma_f32_16x16x32_f16(bf[nf], af[mf], acc[mf][nf], 0, 0, 0);
    } else {
#pragma unroll
      for (int mf = 0; mf < 4; ++mf)
#pragma unroll
        for (int nf = 0; nf < 4; ++nf)
          acc[mf][nf] = __builtin_amdgcn_mfma_f32_16x16x32_f16(af[mf], bf[nf], acc[mf][nf], 0, 0, 0);
    }

    if (t < 23) {
      asm volatile("s_waitcnt vmcnt(0)" ::: "memory");
      __builtin_amdgcn_s_barrier();
      cur ^= 1;
    }
  }

  if constexpr (EPI == 0) {
    // q/k C^T epilogue: arrays per half: 0=q (x1/8), 1=k
    const int t_ = c0 / 768;                 // 0=q, 1=k
    const int rem0 = c0 - t_ * 768;
    unsigned short* arr = ws_split + (size_t)(half * 3 + t_) * SZC;
    const float qs = (t_ == 0) ? 0.125f : 1.0f;
#pragma unroll
    for (int nf = 0; nf < 4; ++nf) {
      const int rem_c = rem0 + wc * 64 + nf * 16 + agrp * 4;
      const int h = rem_c >> 6;
      const int d = rem_c & 63;
      const size_t bh_ = (size_t)(b * HEADS + h);
#pragma unroll
      for (int mf = 0; mf < 4; ++mf) {
        const int n = nloc + wr * 64 + mf * 16 + arow;
        unsigned short hv[4];
#pragma unroll
        for (int ri = 0; ri < 4; ++ri) hv[ri] = f2h(acc[mf][nf][ri] * qs);
        *(ushort4*)(arr + (bh_ * NSEQ + n) * HD + d) = *(ushort4*)hv;
      }
    }
  } else if constexpr (EPI == 3) {
    // v tiles, transposed layout (B,H,64,N): n contiguous over ri
    const int rem0 = c0 - 1536;
    unsigned short* vt_a = ws_split + (size_t)(half * 3 + 2) * SZC;
#pragma unroll
    for (int nf = 0; nf < 4; ++nf) {
      const int rc = rem0 + wc * 64 + nf * 16 + arow;
      const int h = rc >> 6;
      const int d = rc & 63;
      const size_t bh_ = (size_t)(b * HEADS + h);
#pragma unroll
      for (int mf = 0; mf < 4; ++mf) {
        const int n = nloc + wr * 64 + mf * 16 + agrp * 4;
        unsigned short hv[4];
#pragma unroll
        for (int ri = 0; ri < 4; ++ri) hv[ri] = f2h(acc[mf][nf][ri]);
        *(ushort4*)(vt_a + (bh_ * HD + d) * NSEQ + n) = *(ushort4*)hv;
      }
    }
  } else if constexpr (EPI == 1) {
#pragma unroll
    for (int nf = 0; nf < 4; ++nf) {
      const int cg = c0 + wc * 64 + nf * 16 + arow;
      const float bv = bias[cg];
#pragma unroll
      for (int mf = 0; mf < 4; ++mf) {
#pragma unroll
        for (int ri = 0; ri < 4; ++ri) {
          const int m = m0 + wr * 64 + mf * 16 + agrp * 4 + ri;
          const int bb = m >> 10, n = m & 1023;
          outf[(size_t)bb * (2048 * 768) + (size_t)(1024 + n) * 768 + cg] =
              acc[mf][nf][ri] + bv;
        }
      }
    }
  } else {  // EPI == 2: f16 transposed (B,H,64,N)
#pragma unroll
    for (int nf = 0; nf < 4; ++nf) {
      const int cg = c0 + wc * 64 + nf * 16 + arow;
      const int h = cg >> 6, d = cg & 63;
      const float bv = bias[cg];
#pragma unroll
      for (int mf = 0; mf < 4; ++mf) {
        const int m = m0 + wr * 64 + mf * 16 + agrp * 4;
        const int bb = m >> 10, n = m & 1023;
        unsigned short hv[4];
#pragma unroll
        for (int ri = 0; ri < 4; ++ri) hv[ri] = f2h(acc[mf][nf][ri] + bv);
        const size_t idx = ((size_t)(bb * HEADS + h) * HD + d) * NSEQ + n;
        *(ushort4*)(vt_out + idx) = *(ushort4*)hv;
      }
    }
  }
}

// ---------------------------------------------------------------------------
// Flash attention, single-f16 core with fixed-max softmax (R16, unchanged).
// 16 q-rows/wave, grid (16,12,4). Output: osp f16.
// ---------------------------------------------------------------------------
__global__ __launch_bounds__(256) void attn_single_k(
    const unsigned short* __restrict__ q_, const unsigned short* __restrict__ kk_,
    const unsigned short* __restrict__ vt_,
    unsigned short* __restrict__ osp)
{
  __shared__ __attribute__((aligned(16))) unsigned char lds[33792];
  unsigned char* const ldsK = lds;
  unsigned char* const ldsV = lds + 8192;

  const int tid  = threadIdx.x;
  const int wave = tid >> 6;
  const int lane = tid & 63;

  int flat = blockIdx.x + 16 * blockIdx.y + 192 * blockIdx.z;
  flat = (flat & 7) * 96 + (flat >> 3);
  const int bxq = flat & 15;
  const int h = (flat >> 4) % 12;
  const int b = flat / 192;
  const int bh = b * HEADS + h;
  const int q0 = bxq * 64 + wave * 16;

  unsigned int* const ldsP = (unsigned int*)(lds + 16384) + wave * (16 * 68);
  const int arow = lane & 15;
  const int agrp = lane >> 4;

  f16x8 q8[2];
  {
    const unsigned short* qp = q_ + ((size_t)bh * NSEQ + q0 + arow) * HD + agrp * 8;
    q8[0] = *(const f16x8*)qp;
    q8[1] = *(const f16x8*)(qp + 32);
  }

  f32x4 acc[4];
#pragma unroll
  for (int i = 0; i < 4; ++i) acc[i] = f32x4{0.f, 0.f, 0.f, 0.f};
  float l_run[4] = {0.f, 0.f, 0.f, 0.f};

  const int sr = tid >> 3, sc = tid & 7;
  const int swzc = ((sc ^ (sr & 7)) << 3);
  const size_t kbase = (size_t)bh * NSEQ * HD;
  const size_t vbase = (size_t)bh * HD * NSEQ;
  const unsigned short* gK = kk_ + kbase + (size_t)sr * 64 + swzc;
  const unsigned short* gV = vt_ + vbase + (size_t)sr * NSEQ + swzc;
  const int ldsw = (wave * 8) * 128;

  for (int j0 = 0; j0 < NSEQ; j0 += 64) {
    __syncthreads();
    gl16(gK + j0 * 64, ldsK + ldsw);
    gl16(gK + j0 * 64 + 2048, ldsK + ldsw + 4096);
    gl16(gV + j0, ldsV + ldsw);
    gl16(gV + j0 + 32 * NSEQ, ldsV + ldsw + 4096);
    __syncthreads();

    f32x4 s[4];
#pragma unroll
    for (int nt = 0; nt < 4; ++nt) s[nt] = f32x4{0.f, 0.f, 0.f, 0.f};
#pragma unroll
    for (int ks = 0; ks < 2; ++ks) {
#pragma unroll
      for (int nt = 0; nt < 4; ++nt) {
        const int krow = nt * 16 + arow;
        const int chunk = ks * 4 + agrp;
        const int off = krow * 128 + (((chunk ^ (krow & 7)) << 4));
        f16x8 kf = *(const f16x8*)(ldsK + off);
        s[nt] = __builtin_amdgcn_mfma_f32_16x16x32_f16(q8[ks], kf, s[nt], 0, 0, 0);
      }
    }

#pragma unroll
    for (int nt = 0; nt < 4; ++nt) {
#pragma unroll
      for (int r = 0; r < 4; ++r) {
        float p = __expf(s[nt][r]);
        l_run[r] += p;
        ldsP[(agrp * 4 + r) * 68 + nt * 16 + arow] = (unsigned int)f2h(p);
      }
    }

#pragma unroll
    for (int kk = 0; kk < 2; ++kk) {
      const unsigned int* prow = ldsP + arow * 68 + kk * 32 + agrp * 8;
      u32x4v w0 = *(const u32x4v*)prow;
      u32x4v w1 = *(const u32x4v*)(prow + 4);
      bf16x8 raw;
#pragma unroll
      for (int i = 0; i < 4; ++i) {
        raw[i]     = (short)(w0[i] & 0xffffu);
        raw[4 + i] = (short)(w1[i] & 0xffffu);
      }
      f16x8 p8 = *reinterpret_cast<f16x8*>(&raw);
#pragma unroll
      for (int nt2 = 0; nt2 < 4; ++nt2) {
        const int vrow = nt2 * 16 + arow;
        const int chunk = kk * 4 + agrp;
        const int off = vrow * 128 + (((chunk ^ (vrow & 7)) << 4));
        f16x8 vf = *(const f16x8*)(ldsV + off);
        acc[nt2] = __builtin_amdgcn_mfma_f32_16x16x32_f16(p8, vf, acc[nt2], 0, 0, 0);
      }
    }
  }

#pragma unroll
  for (int r = 0; r < 4; ++r) {
    float sm = l_run[r];
    sm += __shfl_xor(sm, 1, 64);
    sm += __shfl_xor(sm, 2, 64);
    sm += __shfl_xor(sm, 4, 64);
    sm += __shfl_xor(sm, 8, 64);
    const float inv = 1.f / sm;
    const int n = q0 + agrp * 4 + r;
    const size_t obase = ((size_t)(b * NSEQ + n)) * C_DIM + h * HD + arow;
#pragma unroll
    for (int nt2 = 0; nt2 < 4; ++nt2)
      osp[obase + nt2 * 16] = f2h(acc[nt2][r] * inv);
  }
}

// ---------------------------------------------------------------------------
// Fused attention (steps 4+5): shared QK^T + exp, two PV passes (R16).
// ---------------------------------------------------------------------------
__global__ __launch_bounds__(256) void attn_fused_k(
    const unsigned short* __restrict__ q_, const unsigned short* __restrict__ kk_,
    const unsigned short* __restrict__ vA_, const unsigned short* __restrict__ vB_,
    float* __restrict__ out1,
    unsigned short* __restrict__ osp)
{
  __shared__ __attribute__((aligned(16))) unsigned char lds[41984];
  unsigned char* const ldsK = lds;
  unsigned char* const ldsA = lds + 8192;
  unsigned char* const ldsB = lds + 16384;

  const int tid  = threadIdx.x;
  const int wave = tid >> 6;
  const int lane = tid & 63;

  int flat = blockIdx.x + 16 * blockIdx.y + 192 * blockIdx.z;
  flat = (flat & 7) * 96 + (flat >> 3);
  const int bxq = flat & 15;
  const int h = (flat >> 4) % 12;
  const int b = flat / 192;
  const int bh = b * HEADS + h;
  const int q0 = bxq * 64 + wave * 16;

  unsigned int* const ldsP = (unsigned int*)(lds + 24576) + wave * (16 * 68);
  const int arow = lane & 15;
  const int agrp = lane >> 4;

  f16x8 q8[2];
  {
    const unsigned short* qp = q_ + ((size_t)bh * NSEQ + q0 + arow) * HD + agrp * 8;
    q8[0] = *(const f16x8*)qp;
    q8[1] = *(const f16x8*)(qp + 32);
  }

  f32x4 acc1[4], acc2[4];
#pragma unroll
  for (int i = 0; i < 4; ++i) {
    acc1[i] = f32x4{0.f, 0.f, 0.f, 0.f};
    acc2[i] = f32x4{0.f, 0.f, 0.f, 0.f};
  }
  float l_run[4] = {0.f, 0.f, 0.f, 0.f};

  const int sr = tid >> 3, sc = tid & 7;
  const int swzc = ((sc ^ (sr & 7)) << 3);
  const size_t kbase = (size_t)bh * NSEQ * HD;
  const size_t vbase = (size_t)bh * HD * NSEQ;
  const unsigned short* gK = kk_ + kbase + (size_t)sr * 64 + swzc;
  const unsigned short* gA = vA_ + vbase + (size_t)sr * NSEQ + swzc;
  const unsigned short* gB = vB_ + vbase + (size_t)sr * NSEQ + swzc;
  const int ldsw = (wave * 8) * 128;

  for (int j0 = 0; j0 < NSEQ; j0 += 64) {
    __syncthreads();
    gl16(gK + j0 * 64, ldsK + ldsw);
    gl16(gK + j0 * 64 + 2048, ldsK + ldsw + 4096);
    gl16(gA + j0, ldsA + ldsw);
    gl16(gA + j0 + 32 * NSEQ, ldsA + ldsw + 4096);
    gl16(gB + j0, ldsB + ldsw);
    gl16(gB + j0 + 32 * NSEQ, ldsB + ldsw + 4096);
    __syncthreads();

    f32x4 s[4];
#pragma unroll
    for (int nt = 0; nt < 4; ++nt) s[nt] = f32x4{0.f, 0.f, 0.f, 0.f};
#pragma unroll
    for (int ks = 0; ks < 2; ++ks) {
#pragma unroll
      for (int nt = 0; nt < 4; ++nt) {
        const int krow = nt * 16 + arow;
        const int chunk = ks * 4 + agrp;
        const int off = krow * 128 + (((chunk ^ (krow & 7)) << 4));
        f16x8 kf = *(const f16x8*)(ldsK + off);
        s[nt] = __builtin_amdgcn_mfma_f32_16x16x32_f16(q8[ks], kf, s[nt], 0, 0, 0);
      }
    }

#pragma unroll
    for (int nt = 0; nt < 4; ++nt) {
#pragma unroll
      for (int r = 0; r < 4; ++r) {
        float p = __expf(s[nt][r]);
        l_run[r] += p;
        ldsP[(agrp * 4 + r) * 68 + nt * 16 + arow] = (unsigned int)f2h(p);
      }
    }

#pragma unroll
    for (int kk = 0; kk < 2; ++kk) {
      const unsigned int* prow = ldsP + arow * 68 + kk * 32 + agrp * 8;
      u32x4v w0 = *(const u32x4v*)prow;
      u32x4v w1 = *(const u32x4v*)(prow + 4);
      bf16x8 raw;
#pragma unroll
      for (int i = 0; i < 4; ++i) {
        raw[i]     = (short)(w0[i] & 0xffffu);
        raw[4 + i] = (short)(w1[i] & 0xffffu);
      }
      f16x8 p8 = *reinterpret_cast<f16x8*>(&raw);
#pragma unroll
      for (int nt2 = 0; nt2 < 4; ++nt2) {
        const int vrow = nt2 * 16 + arow;
        const int chunk = kk * 4 + agrp;
        const int off = vrow * 128 + (((chunk ^ (vrow & 7)) << 4));
        f16x8 va = *(const f16x8*)(ldsA + off);
        f16x8 vb = *(const f16x8*)(ldsB + off);
        acc1[nt2] = __builtin_amdgcn_mfma_f32_16x16x32_f16(p8, va, acc1[nt2], 0, 0, 0);
        acc2[nt2] = __builtin_amdgcn_mfma_f32_16x16x32_f16(p8, vb, acc2[nt2], 0, 0, 0);
      }
    }
  }

#pragma unroll
  for (int r = 0; r < 4; ++r) {
    float sm = l_run[r];
    sm += __shfl_xor(sm, 1, 64);
    sm += __shfl_xor(sm, 2, 64);
    sm += __shfl_xor(sm, 4, 64);
    sm += __shfl_xor(sm, 8, 64);
    const float inv = 1.f / sm;
    const int n = q0 + agrp * 4 + r;
    float* rowp = out1 + (size_t)b * (2048 * C_DIM) + (size_t)n * C_DIM + h * HD + arow;
    const size_t obase = ((size_t)(b * NSEQ + n)) * C_DIM + h * HD + arow;
#pragma unroll
    for (int nt2 = 0; nt2 < 4; ++nt2) {
      rowp[nt2 * 16] = acc1[nt2][r] * inv;
      osp[obase + nt2 * 16] = f2h(acc2[nt2][r] * inv);
    }
  }
}

// ---------------------------------------------------------------------------
extern "C" void kernel_launch(void* const* d_in, const int* in_sizes, int n_in,
                              void* d_out, int out_size, void* d_ws, size_t ws_size,
                              hipStream_t stream)
{
  const float* x           = (const float*)d_in[0];
  const float* w_qkv_diff  = (const float*)d_in[1];
  const float* w_qkv_cond  = (const float*)d_in[2];
  const float* w_proj_diff = (const float*)d_in[3];
  const float* b_proj_diff = (const float*)d_in[4];
  const float* w_proj_cond = (const float*)d_in[5];
  const float* b_proj_cond = (const float*)d_in[6];
  float* out = (float*)d_out;

  const size_t SZ = SZC;
  const size_t WQ = 2304 * 768;
  const size_t WP = 768 * 768;
  unsigned short* sw = (unsigned short*)d_ws;
  // qkv outputs (f16): per half: q, k, vt
  unsigned short* qd  = sw + 0 * SZ;
  unsigned short* kd  = sw + 1 * SZ;
  unsigned short* vtd = sw + 2 * SZ;
  unsigned short* qc  = sw + 3 * SZ;
  unsigned short* kc  = sw + 4 * SZ;
  unsigned short* vtc = sw + 5 * SZ;
  // weights (f16 single)
  unsigned short* wqdT = sw + 6 * SZ;
  unsigned short* wqcT = wqdT + WQ;
  unsigned short* wpdT = wqcT + WQ;
  unsigned short* wpcT = wpdT + WP;
  // osp (f16 single, SZ) after weights
  unsigned short* osp = wpcT + WP;
  // vt2 (f16 single, SZ) aliases qd (dead after step 2)
  unsigned short* vt2 = qd;
  // x f16 scratch: d_out (dead until step 4)
  unsigned short* xs = (unsigned short*)d_out;

  // 0. prep
  split_wT4_k<<<dim3(72, 24, 4), dim3(32, 8), 0, stream>>>(
      w_qkv_diff, w_qkv_cond, w_proj_diff, w_proj_cond,
      wqdT, wqcT, wpdT, wpcT);
  split_x_k<<<dim3(3072), 256, 0, stream>>>(x, xs);

  // 1a. qkv q/k tiles (C^T epilogue)
  gemm2_k<0><<<dim3(12, 32, 2), 256, 0, stream>>>(
      xs, wqdT, wqcT, nullptr, sw, nullptr, nullptr);
  // 1b. qkv v tiles (transposed vt epilogue)
  gemm2_k<3><<<dim3(6, 32, 2), 256, 0, stream>>>(
      xs, wqdT, wqcT, nullptr, sw, nullptr, nullptr);

  // 2. attn_diff -> osp f16
  attn_single_k<<<dim3(16, 12, 4), 256, 0, stream>>>(qd, kd, vtd, osp);

  // 3. (osp @ w_proj_diff + b)^T -> vt2 f16
  gemm2_k<2><<<dim3(6, 32), 256, 0, stream>>>(
      osp, wpdT, nullptr, b_proj_diff, nullptr, nullptr, vt2);

  // 4+5. fused attn_cond: P @ vt2 -> out[:, :N] fp32 ; P @ vtc -> osp f16
  attn_fused_k<<<dim3(16, 12, 4), 256, 0, stream>>>(
      qc, kc, vt2, vtc, out, osp);

  // 6. out[:, N:] = osp @ w_proj_cond + b
  gemm2_k<1><<<dim3(6, 32), 256, 0, stream>>>(
      osp, wpcT, nullptr, b_proj_cond, nullptr, out, nullptr);
}